// Round 1
// baseline (757.067 us; speedup 1.0000x reference)
//
#include <hip/hip_runtime.h>

#define O_N 50000
#define T_N 200000
#define N_N 250000   // O_N + T_N
#define D_N 128
#define GR  128      // rows per GEMM block

// ---------------- degree pipeline ----------------
__global__ void deg_init_kernel(float* __restrict__ deg) {
    int n = blockIdx.x * 256 + threadIdx.x;
    if (n < N_N) deg[n] = (n < T_N) ? 2.0f : 1.0f;   // self-loop + [n<T] (dst=k term)
}

__global__ void deg_edge_kernel(const int* __restrict__ edges, float* __restrict__ deg) {
    int t = blockIdx.x * 256 + threadIdx.x;
    if (t < T_N) atomicAdd(&deg[edges[2 * t + 1]], 1.0f);
}

__global__ void deg_rsqrt_kernel(float* __restrict__ deg) {
    int n = blockIdx.x * 256 + threadIdx.x;
    if (n < N_N) deg[n] = rsqrtf(deg[n]);            // deg >= 1 always (self loop)
}

// ---------------- GEMM: x = in @ W.T, fused self-loop + bias epilogue ----------------
// out[n] = b + x[n] * dinv[n]^2 ; x rows < T stored to ws for the edge kernels.
__launch_bounds__(512, 1)
__global__ void gemm_kernel(const float* __restrict__ obj, const float* __restrict__ pred,
                            const float* __restrict__ W, const float* __restrict__ bias,
                            const float* __restrict__ dinv,
                            float* __restrict__ x_ws, float* __restrict__ out) {
    __shared__ float Wt[128][132];   // Wt[j][d] = W[d][j]; pad 132 keeps 16B align + spreads banks
    __shared__ float rows[GR][128];  // 64 KB input-row tile

    const int tid = threadIdx.x;

    // stage W transposed (one-time, small conflict cost acceptable)
    #pragma unroll
    for (int i = 0; i < 32; ++i) {
        int idx = i * 512 + tid;
        int dd = idx >> 7, jj = idx & 127;
        Wt[jj][dd] = W[idx];
    }

    const long rowBase = (long)blockIdx.x * GR;

    // stage 128 input rows as float4 (coalesced)
    for (int i = tid; i < GR * 32; i += 512) {
        int r = i >> 5, c4 = i & 31;
        long gr = rowBase + r;
        float4 v = make_float4(0.f, 0.f, 0.f, 0.f);
        if (gr < N_N) {
            const float4* src = (gr < O_N)
                ? (const float4*)(obj + gr * 128)
                : (const float4*)(pred + (gr - O_N) * 128);
            v = src[c4];
        }
        ((float4*)rows[r])[c4] = v;
    }
    __syncthreads();

    const int tx = tid & 31, ty = tid >> 5;  // tx: 32 col-groups of 4, ty: 16 row-groups of 8
    const int d0 = tx * 4;

    float acc[8][4];
    #pragma unroll
    for (int rr = 0; rr < 8; ++rr)
        acc[rr][0] = acc[rr][1] = acc[rr][2] = acc[rr][3] = 0.f;

    for (int j = 0; j < 128; j += 4) {
        float4 w0 = *(const float4*)&Wt[j + 0][d0];
        float4 w1 = *(const float4*)&Wt[j + 1][d0];
        float4 w2 = *(const float4*)&Wt[j + 2][d0];
        float4 w3 = *(const float4*)&Wt[j + 3][d0];
        #pragma unroll
        for (int rr = 0; rr < 8; ++rr) {
            float4 v = *(const float4*)&rows[ty * 8 + rr][j];
            acc[rr][0] += v.x * w0.x + v.y * w1.x + v.z * w2.x + v.w * w3.x;
            acc[rr][1] += v.x * w0.y + v.y * w1.y + v.z * w2.y + v.w * w3.y;
            acc[rr][2] += v.x * w0.z + v.y * w1.z + v.z * w2.z + v.w * w3.z;
            acc[rr][3] += v.x * w0.w + v.y * w1.w + v.z * w2.w + v.w * w3.w;
        }
    }

    float4 b4 = *(const float4*)(bias + d0);
    #pragma unroll
    for (int rr = 0; rr < 8; ++rr) {
        long gr = rowBase + ty * 8 + rr;
        if (gr >= N_N) continue;
        float di = dinv[gr];
        float sn = di * di;   // self-loop norm = 1/deg
        float4 xa = make_float4(acc[rr][0], acc[rr][1], acc[rr][2], acc[rr][3]);
        if (gr < T_N) ((float4*)(x_ws + gr * 128))[tx] = xa;
        float4 o = make_float4(xa.x * sn + b4.x, xa.y * sn + b4.y,
                               xa.z * sn + b4.z, xa.w * sn + b4.w);
        ((float4*)(out + gr * 128))[tx] = o;
    }
}

// ---------------- part 1: dst = t (unique) -> non-atomic RMW ----------------
__launch_bounds__(256)
__global__ void part1_kernel(const int* __restrict__ edges, const float* __restrict__ dinv,
                             const float* __restrict__ x_ws, float* __restrict__ out) {
    int t = blockIdx.x * 8 + (threadIdx.x >> 5);
    if (t >= T_N) return;
    int lane = threadIdx.x & 31;
    int e0 = edges[2 * t];
    float nm = dinv[e0] * dinv[t];
    float4 xv = ((const float4*)(x_ws + (long)e0 * 128))[lane];
    float4* orow = (float4*)(out + (long)t * 128);
    float4 o = orow[lane];
    o.x += xv.x * nm; o.y += xv.y * nm; o.z += xv.z * nm; o.w += xv.w * nm;
    orow[lane] = o;
}

// ---------------- part 2: dst = edges[:,1] (collides) -> atomics ----------------
__launch_bounds__(256)
__global__ void part2_kernel(const int* __restrict__ edges, const float* __restrict__ dinv,
                             const float* __restrict__ x_ws, float* __restrict__ out) {
    int t = blockIdx.x * 8 + (threadIdx.x >> 5);
    if (t >= T_N) return;
    int lane = threadIdx.x & 31;
    int e1 = edges[2 * t + 1];
    float nm = dinv[t] * dinv[e1];
    float4 xv = ((const float4*)(x_ws + (long)t * 128))[lane];
    float* orow = out + (long)e1 * 128 + lane * 4;
    atomicAdd(orow + 0, xv.x * nm);
    atomicAdd(orow + 1, xv.y * nm);
    atomicAdd(orow + 2, xv.z * nm);
    atomicAdd(orow + 3, xv.w * nm);
}

extern "C" void kernel_launch(void* const* d_in, const int* in_sizes, int n_in,
                              void* d_out, int out_size, void* d_ws, size_t ws_size,
                              hipStream_t stream) {
    const float* obj   = (const float*)d_in[0];
    const float* pred  = (const float*)d_in[1];
    const int*   edges = (const int*)d_in[2];
    const float* W     = (const float*)d_in[3];
    const float* bias  = (const float*)d_in[4];
    float* out  = (float*)d_out;
    float* x_ws = (float*)d_ws;                       // T_N*128 floats
    float* dinv = x_ws + (size_t)T_N * 128;           // N_N floats

    deg_init_kernel <<<(N_N + 255) / 256, 256, 0, stream>>>(dinv);
    deg_edge_kernel <<<(T_N + 255) / 256, 256, 0, stream>>>(edges, dinv);
    deg_rsqrt_kernel<<<(N_N + 255) / 256, 256, 0, stream>>>(dinv);
    gemm_kernel     <<<(N_N + GR - 1) / GR, 512, 0, stream>>>(obj, pred, W, bias, dinv, x_ws, out);
    part1_kernel    <<<(T_N + 7) / 8, 256, 0, stream>>>(edges, dinv, x_ws, out);
    part2_kernel    <<<(T_N + 7) / 8, 256, 0, stream>>>(edges, dinv, x_ws, out);
}

// Round 3
// 478.592 us; speedup vs baseline: 1.5819x; 1.5819x over previous
//
#include <hip/hip_runtime.h>

#define O_N 50000
#define T_N 200000
#define N_N 250000   // O_N + T_N
#define D_N 128
#define GR  128      // rows per GEMM block
#define BCAP 32      // CSR bucket capacity (Poisson lambda=4; P(deg>=32) ~ 1e-18)
#define OFCAP 4096   // overflow list capacity

// ---------------- CSR build: histogram + bucket scatter ----------------
__global__ void scatter_kernel(const int* __restrict__ edges, int* __restrict__ cnt,
                               int* __restrict__ bucket, int* __restrict__ oflow_cnt,
                               int* __restrict__ oflow) {
    int t = blockIdx.x * 256 + threadIdx.x;
    if (t >= T_N) return;
    int e1 = edges[2 * t + 1];
    int pos = atomicAdd(&cnt[e1], 1);
    if (pos < BCAP) bucket[e1 * BCAP + pos] = t;
    else { int p = atomicAdd(oflow_cnt, 1); if (p < OFCAP) oflow[p] = t; }
}

// dinv analytically from histogram: deg = self(1) + part1-dst(n<T) + hist(n<O)
__global__ void dinv_kernel(const int* __restrict__ cnt, float* __restrict__ dinv) {
    int n = blockIdx.x * 256 + threadIdx.x;
    if (n >= N_N) return;
    float deg;
    if (n < O_N)      deg = 2.0f + (float)cnt[n];
    else if (n < T_N) deg = 2.0f;
    else              deg = 1.0f;
    dinv[n] = rsqrtf(deg);
}

// ---------------- GEMM: x = in @ W.T, fused self-loop + bias epilogue ----------------
__launch_bounds__(512, 1)
__global__ void gemm_kernel(const float* __restrict__ obj, const float* __restrict__ pred,
                            const float* __restrict__ W, const float* __restrict__ bias,
                            const float* __restrict__ dinv,
                            float* __restrict__ x_ws, float* __restrict__ out) {
    __shared__ float Wt[128][132];
    __shared__ float rows[GR][128];

    const int tid = threadIdx.x;

    #pragma unroll
    for (int i = 0; i < 32; ++i) {
        int idx = i * 512 + tid;
        int dd = idx >> 7, jj = idx & 127;
        Wt[jj][dd] = W[idx];
    }

    const long rowBase = (long)blockIdx.x * GR;

    for (int i = tid; i < GR * 32; i += 512) {
        int r = i >> 5, c4 = i & 31;
        long gr = rowBase + r;
        float4 v = make_float4(0.f, 0.f, 0.f, 0.f);
        if (gr < N_N) {
            const float4* src = (gr < O_N)
                ? (const float4*)(obj + gr * 128)
                : (const float4*)(pred + (gr - O_N) * 128);
            v = src[c4];
        }
        ((float4*)rows[r])[c4] = v;
    }
    __syncthreads();

    const int tx = tid & 31, ty = tid >> 5;
    const int d0 = tx * 4;

    float acc[8][4];
    #pragma unroll
    for (int rr = 0; rr < 8; ++rr)
        acc[rr][0] = acc[rr][1] = acc[rr][2] = acc[rr][3] = 0.f;

    for (int j = 0; j < 128; j += 4) {
        float4 w0 = *(const float4*)&Wt[j + 0][d0];
        float4 w1 = *(const float4*)&Wt[j + 1][d0];
        float4 w2 = *(const float4*)&Wt[j + 2][d0];
        float4 w3 = *(const float4*)&Wt[j + 3][d0];
        #pragma unroll
        for (int rr = 0; rr < 8; ++rr) {
            float4 v = *(const float4*)&rows[ty * 8 + rr][j];
            acc[rr][0] += v.x * w0.x + v.y * w1.x + v.z * w2.x + v.w * w3.x;
            acc[rr][1] += v.x * w0.y + v.y * w1.y + v.z * w2.y + v.w * w3.y;
            acc[rr][2] += v.x * w0.z + v.y * w1.z + v.z * w2.z + v.w * w3.z;
            acc[rr][3] += v.x * w0.w + v.y * w1.w + v.z * w2.w + v.w * w3.w;
        }
    }

    float4 b4 = *(const float4*)(bias + d0);
    #pragma unroll
    for (int rr = 0; rr < 8; ++rr) {
        long gr = rowBase + ty * 8 + rr;
        if (gr >= N_N) continue;
        float di = dinv[gr];
        float sn = di * di;
        float4 xa = make_float4(acc[rr][0], acc[rr][1], acc[rr][2], acc[rr][3]);
        if (gr < T_N) ((float4*)(x_ws + gr * 128))[tx] = xa;
        float4 o = make_float4(xa.x * sn + b4.x, xa.y * sn + b4.y,
                               xa.z * sn + b4.z, xa.w * sn + b4.w);
        ((float4*)(out + gr * 128))[tx] = o;
    }
}

// ---------------- part 1 (t in [O,T)): dst = t unique -> non-atomic RMW ----------------
__launch_bounds__(256)
__global__ void part1_kernel(const int* __restrict__ edges, const float* __restrict__ dinv,
                             const float* __restrict__ x_ws, float* __restrict__ out) {
    int t = O_N + blockIdx.x * 8 + (threadIdx.x >> 5);
    if (t >= T_N) return;
    int lane = threadIdx.x & 31;
    int e0 = edges[2 * t];
    float nm = dinv[e0] * dinv[t];
    float4 xv = ((const float4*)(x_ws + (long)e0 * 128))[lane];
    float4* orow = (float4*)(out + (long)t * 128);
    float4 o = orow[lane];
    o.x += xv.x * nm; o.y += xv.y * nm; o.z += xv.z * nm; o.w += xv.w * nm;
    orow[lane] = o;
}

// ---------------- gather: one wave per object o; absorbs part-1 edge for t=o ----------------
__launch_bounds__(256)
__global__ void gather_kernel(const int* __restrict__ edges, const int* __restrict__ cnt,
                              const int* __restrict__ bucket, const float* __restrict__ dinv,
                              const float* __restrict__ x_ws, float* __restrict__ out) {
    int o = blockIdx.x * 4 + (threadIdx.x >> 6);
    if (o >= O_N) return;
    int lane = threadIdx.x & 63;
    float dio = dinv[o];

    // part-1 edge with dst=o (src = edges[o][0])
    int e0 = edges[2 * o];
    float nm0 = dinv[e0] * dio;
    float2 v0 = ((const float2*)(x_ws + (long)e0 * 128))[lane];
    float2 acc = make_float2(v0.x * nm0, v0.y * nm0);

    // part-2 in-edges (src = t, dst = o)
    int c = cnt[o]; if (c > BCAP) c = BCAP;
    for (int i = 0; i < c; ++i) {
        int t = bucket[o * BCAP + i];
        float nm = dinv[t] * dio;
        float2 v = ((const float2*)(x_ws + (long)t * 128))[lane];
        acc.x += v.x * nm; acc.y += v.y * nm;
    }

    float2* orow = (float2*)(out + (long)o * 128);
    float2 ov = orow[lane];
    ov.x += acc.x; ov.y += acc.y;
    orow[lane] = ov;
}

// ---------------- overflow fallback (practically never runs; correctness net) ----------------
__launch_bounds__(256)
__global__ void oflow_kernel(const int* __restrict__ edges, const int* __restrict__ oflow_cnt,
                             const int* __restrict__ oflow, const float* __restrict__ dinv,
                             const float* __restrict__ x_ws, float* __restrict__ out) {
    int nc = *oflow_cnt; if (nc > OFCAP) nc = OFCAP;
    int gid = blockIdx.x * 8 + (threadIdx.x >> 5);
    int lane = threadIdx.x & 31;
    for (int i = gid; i < nc; i += gridDim.x * 8) {
        int t = oflow[i];
        int e1 = edges[2 * t + 1];
        float nm = dinv[t] * dinv[e1];
        float4 v = ((const float4*)(x_ws + (long)t * 128))[lane];
        float* orow = out + (long)e1 * 128 + lane * 4;
        atomicAdd(orow + 0, v.x * nm);
        atomicAdd(orow + 1, v.y * nm);
        atomicAdd(orow + 2, v.z * nm);
        atomicAdd(orow + 3, v.w * nm);
    }
}

extern "C" void kernel_launch(void* const* d_in, const int* in_sizes, int n_in,
                              void* d_out, int out_size, void* d_ws, size_t ws_size,
                              hipStream_t stream) {
    const float* obj   = (const float*)d_in[0];
    const float* pred  = (const float*)d_in[1];
    const int*   edges = (const int*)d_in[2];
    const float* W     = (const float*)d_in[3];
    const float* bias  = (const float*)d_in[4];
    float* out  = (float*)d_out;

    float* x_ws      = (float*)d_ws;                    // 25,600,000 f
    float* dinv      = x_ws + (size_t)T_N * 128;        // 250,000 f
    int*   cnt       = (int*)(dinv + N_N);              // 50,000 i
    int*   oflow_cnt = cnt + O_N;                       // 1 i
    int*   oflow     = oflow_cnt + 1;                   // 4096 i
    int*   bucket    = oflow + OFCAP;                   // 1,600,000 i

    hipMemsetAsync(cnt, 0, (O_N + 1) * sizeof(int), stream);  // cnt + oflow_cnt

    scatter_kernel<<<(T_N + 255) / 256, 256, 0, stream>>>(edges, cnt, bucket, oflow_cnt, oflow);
    dinv_kernel   <<<(N_N + 255) / 256, 256, 0, stream>>>(cnt, dinv);
    gemm_kernel   <<<(N_N + GR - 1) / GR, 512, 0, stream>>>(obj, pred, W, bias, dinv, x_ws, out);
    part1_kernel  <<<(T_N - O_N + 7) / 8, 256, 0, stream>>>(edges, dinv, x_ws, out);
    gather_kernel <<<(O_N + 3) / 4, 256, 0, stream>>>(edges, cnt, bucket, dinv, x_ws, out);
    oflow_kernel  <<<16, 256, 0, stream>>>(edges, oflow_cnt, oflow, dinv, x_ws, out);
}

// Round 4
// 362.583 us; speedup vs baseline: 2.0880x; 1.3200x over previous
//
#include <hip/hip_runtime.h>

#define O_N 50000
#define T_N 200000
#define N_N 250000
#define BCAP 32
#define OFCAP 4096

typedef __attribute__((ext_vector_type(8))) __bf16 bf16x8;
typedef __attribute__((ext_vector_type(4))) float f32x4;
typedef __attribute__((ext_vector_type(4))) unsigned short us4;

union frag_u { us4 h[2]; bf16x8 v; };

__device__ __forceinline__ unsigned short f2bf(float f) {   // RNE fp32->bf16
    union { float f; unsigned u; } v; v.f = f;
    unsigned r = v.u + 0x7FFFu + ((v.u >> 16) & 1u);
    return (unsigned short)(r >> 16);
}

// XOR-swizzled element offset (T2): 16B slots permuted by row&7 within each row
__device__ __forceinline__ int swoff(int row, int k) {
    return row * 128 + ((((k >> 3) & 15) ^ (row & 7)) << 3) + (k & 7);
}

// ---------------- CSR build: histogram + bucket scatter ----------------
__global__ void scatter_kernel(const int* __restrict__ edges, int* __restrict__ cnt,
                               int* __restrict__ bucket, int* __restrict__ oflow_cnt,
                               int* __restrict__ oflow) {
    int t = blockIdx.x * 256 + threadIdx.x;
    if (t >= T_N) return;
    int e1 = edges[2 * t + 1];
    int pos = atomicAdd(&cnt[e1], 1);
    if (pos < BCAP) bucket[e1 * BCAP + pos] = t;
    else { int p = atomicAdd(oflow_cnt, 1); if (p < OFCAP) oflow[p] = t; }
}

__global__ void dinv_kernel(const int* __restrict__ cnt, float* __restrict__ dinv) {
    int n = blockIdx.x * 256 + threadIdx.x;
    if (n >= N_N) return;
    float deg;
    if (n < O_N)      deg = 2.0f + (float)cnt[n];
    else if (n < T_N) deg = 2.0f;
    else              deg = 1.0f;
    dinv[n] = rsqrtf(deg);
}

// ---------------- bf16 MFMA GEMM: dst rows [nodeBase, nodeEnd) ----------------
// STORE_OUT=0: dst = x_ws (raw x, fp32). STORE_OUT=1: dst = out = x + bias (deg=1 rows).
template<int STORE_OUT>
__launch_bounds__(256, 2)
__global__ void gemm_kernel(const float* __restrict__ src, const float* __restrict__ W,
                            const float* __restrict__ bias, float* __restrict__ dst,
                            int nodeBase, int nodeEnd, int srcNodeOff) {
    __shared__ unsigned short As[128 * 128];   // 32 KB, swizzled bf16
    __shared__ unsigned short Ws[128 * 128];   // 32 KB, swizzled bf16

    const int tid = threadIdx.x;
    const int tileBase = nodeBase + blockIdx.x * 128;

    // stage A: 128 rows x 128 k, fp32 float4 coalesced -> bf16 -> swizzled ds_write
    for (int i = 0; i < 16; ++i) {
        int c = tid + 256 * i;                 // 0..4095
        int r = c >> 5, k4 = (c & 31) << 2;
        int gn = tileBase + r;
        float4 v = make_float4(0.f, 0.f, 0.f, 0.f);
        if (gn < nodeEnd)
            v = *(const float4*)(src + (long)(gn - srcNodeOff) * 128 + k4);
        us4 b; b.x = f2bf(v.x); b.y = f2bf(v.y); b.z = f2bf(v.z); b.w = f2bf(v.w);
        *(us4*)&As[swoff(r, k4)] = b;
    }
    // stage W (row n = output col, k inner) — same swizzle
    for (int i = 0; i < 16; ++i) {
        int c = tid + 256 * i;
        int r = c >> 5, k4 = (c & 31) << 2;
        float4 v = *(const float4*)(W + r * 128 + k4);
        us4 b; b.x = f2bf(v.x); b.y = f2bf(v.y); b.z = f2bf(v.z); b.w = f2bf(v.w);
        *(us4*)&Ws[swoff(r, k4)] = b;
    }
    __syncthreads();

    const int w = tid >> 6, lane = tid & 63;
    const int g = lane >> 4, li = lane & 15;
    const int wr = (w >> 1) * 64, wc = (w & 1) * 64;   // wave's 64x64 quadrant

    const f32x4 fz = {0.f, 0.f, 0.f, 0.f};
    f32x4 acc[4][4];
    #pragma unroll
    for (int i = 0; i < 4; ++i)
        #pragma unroll
        for (int j = 0; j < 4; ++j) acc[i][j] = fz;

    // K = 128 in 4 chunks of 32; A-frag elem j: k = kb + (j&3) + 16*(j>>2), row = li
    #pragma unroll
    for (int kc = 0; kc < 4; ++kc) {
        const int kb = kc * 32 + g * 4;
        frag_u a[4], b[4];
        #pragma unroll
        for (int fr = 0; fr < 4; ++fr) {
            int row = wr + fr * 16 + li;
            a[fr].h[0] = *(const us4*)&As[swoff(row, kb)];
            a[fr].h[1] = *(const us4*)&As[swoff(row, kb + 16)];
        }
        #pragma unroll
        for (int fc = 0; fc < 4; ++fc) {
            int row = wc + fc * 16 + li;
            b[fc].h[0] = *(const us4*)&Ws[swoff(row, kb)];
            b[fc].h[1] = *(const us4*)&Ws[swoff(row, kb + 16)];
        }
        #pragma unroll
        for (int fr = 0; fr < 4; ++fr)
            #pragma unroll
            for (int fc = 0; fc < 4; ++fc)
                acc[fr][fc] = __builtin_amdgcn_mfma_f32_16x16x32_bf16(
                    a[fr].v, b[fc].v, acc[fr][fc], 0, 0, 0);
    }

    // D: col = li (+16*fc +wc), row = 4*g + reg (+16*fr +wr); 16-lane 64B-contig stores
    #pragma unroll
    for (int fr = 0; fr < 4; ++fr) {
        #pragma unroll
        for (int reg = 0; reg < 4; ++reg) {
            int row = tileBase + wr + fr * 16 + g * 4 + reg;
            if (row >= nodeEnd) continue;
            #pragma unroll
            for (int fc = 0; fc < 4; ++fc) {
                int col = wc + fc * 16 + li;
                float val = acc[fr][fc][reg];
                if (STORE_OUT) dst[(long)row * 128 + col] = val + bias[col];
                else           dst[(long)row * 128 + col] = val;
            }
        }
    }
}

// ---------------- part 1 rows n in [O,T): pure write, no RMW ----------------
// out[n] = b + 0.5*x[n] + (dinv[e0]/sqrt2)*x[e0]
__launch_bounds__(256)
__global__ void part1_kernel(const int* __restrict__ edges, const float* __restrict__ dinv,
                             const float* __restrict__ x_ws, const float* __restrict__ bias,
                             float* __restrict__ out) {
    int n = O_N + blockIdx.x * 8 + (threadIdx.x >> 5);
    if (n >= T_N) return;
    int lane = threadIdx.x & 31;
    int e0 = edges[2 * n];
    float nm = dinv[e0] * 0.70710678118654752f;
    float4 xn = ((const float4*)(x_ws + (long)n * 128))[lane];
    float4 xe = ((const float4*)(x_ws + (long)e0 * 128))[lane];
    float4 b4 = ((const float4*)bias)[lane];
    float4 o;
    o.x = b4.x + 0.5f * xn.x + nm * xe.x;
    o.y = b4.y + 0.5f * xn.y + nm * xe.y;
    o.z = b4.z + 0.5f * xn.z + nm * xe.z;
    o.w = b4.w + 0.5f * xn.w + nm * xe.w;
    ((float4*)(out + (long)n * 128))[lane] = o;
}

// ---------------- gather obj rows o in [0,O): pure write ----------------
// out[o] = b + dinv_o^2 * x[o] + dinv[e0]*dinv_o*x[e0] + sum_t dinv[t]*dinv_o*x[t]
__launch_bounds__(256)
__global__ void gather_kernel(const int* __restrict__ edges, const int* __restrict__ cnt,
                              const int* __restrict__ bucket, const float* __restrict__ dinv,
                              const float* __restrict__ x_ws, const float* __restrict__ bias,
                              float* __restrict__ out) {
    int o = blockIdx.x * 4 + (threadIdx.x >> 6);
    if (o >= O_N) return;
    int lane = threadIdx.x & 63;
    float dio = dinv[o];

    float2 b2 = ((const float2*)bias)[lane];
    float2 xo = ((const float2*)(x_ws + (long)o * 128))[lane];
    float sn = dio * dio;
    float2 acc = make_float2(b2.x + sn * xo.x, b2.y + sn * xo.y);

    int e0 = edges[2 * o];
    float nm0 = dinv[e0] * dio;
    float2 v0 = ((const float2*)(x_ws + (long)e0 * 128))[lane];
    acc.x += v0.x * nm0; acc.y += v0.y * nm0;

    int c = cnt[o]; if (c > BCAP) c = BCAP;
    for (int i = 0; i < c; ++i) {
        int t = bucket[o * BCAP + i];
        float nm = dinv[t] * dio;
        float2 v = ((const float2*)(x_ws + (long)t * 128))[lane];
        acc.x += v.x * nm; acc.y += v.y * nm;
    }
    ((float2*)(out + (long)o * 128))[lane] = acc;
}

// ---------------- overflow fallback (rare; atomics AFTER gather's store) ----------------
__launch_bounds__(256)
__global__ void oflow_kernel(const int* __restrict__ edges, const int* __restrict__ oflow_cnt,
                             const int* __restrict__ oflow, const float* __restrict__ dinv,
                             const float* __restrict__ x_ws, float* __restrict__ out) {
    int nc = *oflow_cnt; if (nc > OFCAP) nc = OFCAP;
    int gid = blockIdx.x * 8 + (threadIdx.x >> 5);
    int lane = threadIdx.x & 31;
    for (int i = gid; i < nc; i += gridDim.x * 8) {
        int t = oflow[i];
        int e1 = edges[2 * t + 1];
        float nm = dinv[t] * dinv[e1];
        float4 v = ((const float4*)(x_ws + (long)t * 128))[lane];
        float* orow = out + (long)e1 * 128 + lane * 4;
        atomicAdd(orow + 0, v.x * nm);
        atomicAdd(orow + 1, v.y * nm);
        atomicAdd(orow + 2, v.z * nm);
        atomicAdd(orow + 3, v.w * nm);
    }
}

extern "C" void kernel_launch(void* const* d_in, const int* in_sizes, int n_in,
                              void* d_out, int out_size, void* d_ws, size_t ws_size,
                              hipStream_t stream) {
    const float* obj   = (const float*)d_in[0];
    const float* pred  = (const float*)d_in[1];
    const int*   edges = (const int*)d_in[2];
    const float* W     = (const float*)d_in[3];
    const float* bias  = (const float*)d_in[4];
    float* out  = (float*)d_out;

    float* x_ws      = (float*)d_ws;                    // 25,600,000 f (fp32, nodes [0,T))
    float* dinv      = x_ws + (size_t)T_N * 128;        // 250,000 f
    int*   cnt       = (int*)(dinv + N_N);              // 50,000 i
    int*   oflow_cnt = cnt + O_N;                       // 1 i
    int*   oflow     = oflow_cnt + 1;                   // 4096 i
    int*   bucket    = oflow + OFCAP;                   // 1,600,000 i

    hipMemsetAsync(cnt, 0, (O_N + 1) * sizeof(int), stream);

    scatter_kernel<<<(T_N + 255) / 256, 256, 0, stream>>>(edges, cnt, bucket, oflow_cnt, oflow);
    dinv_kernel   <<<(N_N + 255) / 256, 256, 0, stream>>>(cnt, dinv);

    // obj nodes [0, O): x only
    gemm_kernel<0><<<(O_N + 127) / 128, 256, 0, stream>>>(obj,  W, bias, x_ws, 0,    O_N, 0);
    // pred nodes [O, T): x only (out composed by part1)
    gemm_kernel<0><<<(T_N - O_N + 127) / 128, 256, 0, stream>>>(pred, W, bias, x_ws, O_N, T_N, O_N);
    // pred nodes [T, N): deg=1 -> out = x + b directly, no x_ws
    gemm_kernel<1><<<(N_N - T_N + 127) / 128, 256, 0, stream>>>(pred, W, bias, out, T_N, N_N, O_N);

    part1_kernel <<<(T_N - O_N + 7) / 8, 256, 0, stream>>>(edges, dinv, x_ws, bias, out);
    gather_kernel<<<(O_N + 3) / 4, 256, 0, stream>>>(edges, cnt, bucket, dinv, x_ws, bias, out);
    oflow_kernel <<<16, 256, 0, stream>>>(edges, oflow_cnt, oflow, dinv, x_ws, out);
}